// Round 8
// baseline (265.487 us; speedup 1.0000x reference)
//
#include <hip/hip_runtime.h>
#include <math.h>

#define NE 256
#define EDIM 1024
#define HW 1024
#define NPIX 16384
#define OUT_ELEMS 16777216

typedef short short8 __attribute__((ext_vector_type(8)));
typedef float f32x4 __attribute__((ext_vector_type(4)));

// ---------------- fast-path workspace layout (bytes) ----------------
// [k_prep-zeroed head: hist + ctrl + flag-bitmap]
#define WS_HIST   0          // int[256]
#define WS_LOSS   1024       // float
#define WS_ZSQ    1028       // float
#define WS_FBITS  2048       // uint[512] bitmap of tie-flagged pixels
#define WS_T      4096       // float[1024*256] = 1 MB (zeroed by k_prep)
#define WS_CE2    1052672    // float[256]
#define WS_IDX    1053696    // int[16384]
#define WS_EH     1119232    // ushort[256*1024] = 512 KB, PERMUTED [g][code][8]
#define WS_EL     1643520    // ushort[256*1024] = 512 KB, PERMUTED
#define WS_NEED   2167808

#define DELTA 0.02f          // tie-guard; trunc-split bf16x3 score sigma ~3.5e-4 -> ~57 sigma

// ---------------- fallback (round-1) workspace layout ----------------
#define WO_CE2  0
#define WO_HIST 1024
#define WO_LOSS 2048
#define WO_IDX  4096
#define WO_T    69632
#define WO_TOTAL 1118208

// trunc-split of two fp32 into packed bf16 high parts + packed bf16 residuals.
// h = bit-truncated top 16; r = a - h is EXACT in fp32; l = trunc16(r).
// Dropped error <= 2^-16|a| per term -> bf16x3 score sigma ~3.5e-4.
__device__ __forceinline__ void cvt_pair(float a, float b,
                                         unsigned& hp, unsigned& lp) {
    unsigned ua = __float_as_uint(a), ub = __float_as_uint(b);
    hp = __builtin_amdgcn_perm(ub, ua, 0x07060302u);   // [ua.hi16 | ub.hi16]
    float ra = a - __uint_as_float(ua & 0xFFFF0000u);
    float rb = b - __uint_as_float(ub & 0xFFFF0000u);
    lp = __builtin_amdgcn_perm(__float_as_uint(rb), __float_as_uint(ra), 0x07060302u);
}

__device__ __forceinline__ unsigned short f2bf(float f) {
    unsigned u = __float_as_uint(f);
    unsigned r = u + 0x7FFFu + ((u >> 16) & 1u);   // RNE
    return (unsigned short)(r >> 16);
}

// async global->LDS, 16 B per lane; lds addr must be lane-linear (HW: wavebase+lane*16)
__device__ __forceinline__ void stage16(const void* g, void* l) {
    __builtin_amdgcn_global_load_lds(
        (const __attribute__((address_space(1))) unsigned int*)g,
        (__attribute__((address_space(3))) unsigned int*)l, 16, 0, 0);
}

// ------- prep: emb -> ehs/els (permuted bf16 split), ce2, zero T + head ----
// ehs[(g*256 + j)*8 + jj] = trunc-bf16 of emb[j][g*8+jj], g = k-group 0..127.
__global__ __launch_bounds__(64) void k_prep(const float* __restrict__ emb,
                                             unsigned short* __restrict__ ehs,
                                             unsigned short* __restrict__ els,
                                             float* __restrict__ ce2,
                                             float* __restrict__ T,
                                             unsigned char* __restrict__ head) {
    int j = blockIdx.x;
    int l = threadIdx.x;
    // zero this code's T slab (1024 floats) -- replaces hipMemsetAsync
    f32x4 z4 = {0.f, 0.f, 0.f, 0.f};
    #pragma unroll
    for (int i = 0; i < 4; i++)
        *(f32x4*)(T + ((size_t)j << 10) + l * 4 + 256 * i) = z4;
    if (j == 0) {   // zero hist/loss/zsq/fbits region [0,4096)
        #pragma unroll
        for (int i = 0; i < 4; i++)
            *(uint4*)(head + l * 64 + i * 16) = make_uint4(0, 0, 0, 0);
    }
    const float* row = emb + ((size_t)j << 10);
    float s = 0.f;
    #pragma unroll
    for (int g2 = 0; g2 < 2; g2++) {
        int g = 2 * l + g2;
        float4 va = *(const float4*)(row + g * 8);
        float4 vb = *(const float4*)(row + g * 8 + 4);
        s += va.x * va.x + va.y * va.y + va.z * va.z + va.w * va.w
           + vb.x * vb.x + vb.y * vb.y + vb.z * vb.z + vb.w * vb.w;
        uint4 hq, lq;
        cvt_pair(va.x, va.y, hq.x, lq.x);
        cvt_pair(va.z, va.w, hq.y, lq.y);
        cvt_pair(vb.x, vb.y, hq.z, lq.z);
        cvt_pair(vb.z, vb.w, hq.w, lq.w);
        *(uint4*)(ehs + ((size_t)(g * 256 + j)) * 8) = hq;
        *(uint4*)(els + ((size_t)(g * 256 + j)) * 8) = lq;
    }
    #pragma unroll
    for (int m = 32; m; m >>= 1) s += __shfl_down(s, m, 64);
    if (l == 0) ce2[j] = 0.5f * s;
}

// ---------------- T[o][j] = sum_c w[o][c]*emb[j][c] (split-K, atomics) ----
__global__ __launch_bounds__(256) void k_wT(const float* __restrict__ w,
                                            const float* __restrict__ emb,
                                            float* __restrict__ T) {
    __shared__ float wt[64 * 17];
    __shared__ float et[64 * 17];
    int t = threadIdx.x;
    int j0 = blockIdx.x * 64;
    int o0 = blockIdx.y * 64;
    int kb = blockIdx.z * 256;
    int to = t & 15, tj = t >> 4;
    float acc[4][4] = {};
    int lr = t >> 2, lk = (t & 3) * 4;
    for (int kk = kb; kk < kb + 256; kk += 16) {
        float4 wv = *(const float4*)(w + (size_t)(o0 + lr) * EDIM + kk + lk);
        float4 ev = *(const float4*)(emb + (size_t)(j0 + lr) * EDIM + kk + lk);
        __syncthreads();
        wt[lr * 17 + lk + 0] = wv.x; wt[lr * 17 + lk + 1] = wv.y;
        wt[lr * 17 + lk + 2] = wv.z; wt[lr * 17 + lk + 3] = wv.w;
        et[lr * 17 + lk + 0] = ev.x; et[lr * 17 + lk + 1] = ev.y;
        et[lr * 17 + lk + 2] = ev.z; et[lr * 17 + lk + 3] = ev.w;
        __syncthreads();
        #pragma unroll
        for (int k = 0; k < 16; k++) {
            float a[4], b[4];
            #pragma unroll
            for (int i = 0; i < 4; i++) a[i] = wt[(to * 4 + i) * 17 + k];
            #pragma unroll
            for (int i = 0; i < 4; i++) b[i] = et[(tj * 4 + i) * 17 + k];
            #pragma unroll
            for (int i = 0; i < 4; i++)
                #pragma unroll
                for (int jx = 0; jx < 4; jx++) acc[i][jx] += a[i] * b[jx];
        }
    }
    #pragma unroll
    for (int i = 0; i < 4; i++)
        #pragma unroll
        for (int jx = 0; jx < 4; jx++)
            atomicAdd(&T[(size_t)(o0 + to * 4 + i) * NE + j0 + tj * 4 + jx],
                      acc[i][jx]);
}

// ---------------- fused bf16x3 distance GEMM + argmin + tie-flagging -------
// 256 blocks x 512 thr (8 waves, 2/SIMD). Block = 64 px; wave w owns codes
// [w*32, w*32+32) x all 64 px x full K (code-split -> 4x fewer LDS B-reads).
// B staged via global_load_lds in permuted layout -> 2-way banks (free).
// A (z) register-prefetched 1 chunk ahead, trunc-split to bf16 h/l inline.
__global__ __launch_bounds__(512) void k_dist(
        const float* __restrict__ z, const unsigned short* __restrict__ ehs,
        const unsigned short* __restrict__ els,
        const float* __restrict__ ce2,
        int* __restrict__ idx_i, float* __restrict__ idx_f,
        int* __restrict__ hist, float* __restrict__ loss_s,
        float* __restrict__ zsq_acc, unsigned int* __restrict__ fbits) {
    __shared__ unsigned short sB[2][2][8192];   // [buf][h/l][(quad*256+code)*8] 64 KB
    __shared__ float red[8 * 64 * 3];           // per-wave (v1,i1,v2) x 64 px
    int t = threadIdx.x;
    int lane = t & 63, w = t >> 6;
    int m = lane & 15, quad = lane >> 4;
    int px0 = blockIdx.x * 64;                  // never crosses a batch image
    int b = px0 >> 10;
    const float* zb = z + (((size_t)b) << 20) + (px0 & 1023);

    f32x4 acc[4][2];
    #pragma unroll
    for (int at = 0; at < 4; at++)
        #pragma unroll
        for (int ct = 0; ct < 2; ct++) acc[at][ct] = (f32x4){0.f, 0.f, 0.f, 0.f};

    // stage chunk 0 into buf 0 (lane-linear: 512 thr x 16 B x 2 calls = 16 KB/array)
    stage16(ehs + t * 8,        &sB[0][0][t * 8]);
    stage16(ehs + 4096 + t * 8, &sB[0][0][4096 + t * 8]);
    stage16(els + t * 8,        &sB[0][1][t * 8]);
    stage16(els + 4096 + t * 8, &sB[0][1][4096 + t * 8]);
    // prefetch A chunk 0: zv[at][j] = z[k=quad*8+j][px0 + at*16 + m]
    float zv[4][8];
    #pragma unroll
    for (int at = 0; at < 4; at++)
        #pragma unroll
        for (int j = 0; j < 8; j++)
            zv[at][j] = zb[(((size_t)(quad * 8 + j)) << 10) + at * 16 + m];

    float zsq = 0.f;
    for (int ck = 0; ck < 32; ck++) {
        int cur = ck & 1;
        __syncthreads();                 // drains stage(ck) + A(ck); other buf free
        short8 ah[4], al[4];
        #pragma unroll
        for (int at = 0; at < 4; at++)
            #pragma unroll
            for (int p = 0; p < 4; p++) {
                float a0 = zv[at][2 * p], a1 = zv[at][2 * p + 1];
                unsigned hp, lp;
                cvt_pair(a0, a1, hp, lp);
                ((unsigned*)&ah[at])[p] = hp;
                ((unsigned*)&al[at])[p] = lp;
                if (w == 0) zsq += a0 * a0 + a1 * a1;   // wave 0 covers all px,k
            }
        if (ck < 31) {
            const unsigned short* ep = ehs + (ck + 1) * 8192;
            const unsigned short* lp2 = els + (ck + 1) * 8192;
            stage16(ep + t * 8,         &sB[1 - cur][0][t * 8]);
            stage16(ep + 4096 + t * 8,  &sB[1 - cur][0][4096 + t * 8]);
            stage16(lp2 + t * 8,        &sB[1 - cur][1][t * 8]);
            stage16(lp2 + 4096 + t * 8, &sB[1 - cur][1][4096 + t * 8]);
            #pragma unroll
            for (int at = 0; at < 4; at++)
                #pragma unroll
                for (int j = 0; j < 8; j++)
                    zv[at][j] = zb[(((size_t)((ck + 1) * 32 + quad * 8 + j)) << 10)
                                   + at * 16 + m];
        }
        #pragma unroll
        for (int ct = 0; ct < 2; ct++) {
            int crow = (quad * 256 + w * 32 + ct * 16 + m) * 8;
            short8 bh = *(const short8*)&sB[cur][0][crow];
            short8 bl = *(const short8*)&sB[cur][1][crow];
            #pragma unroll
            for (int at = 0; at < 4; at++) {
                acc[at][ct] = __builtin_amdgcn_mfma_f32_16x16x32_bf16(ah[at], bh, acc[at][ct], 0, 0, 0);
                acc[at][ct] = __builtin_amdgcn_mfma_f32_16x16x32_bf16(ah[at], bl, acc[at][ct], 0, 0, 0);
                acc[at][ct] = __builtin_amdgcn_mfma_f32_16x16x32_bf16(al[at], bh, acc[at][ct], 0, 0, 0);
            }
        }
    }

    if (w == 0) {
        #pragma unroll
        for (int msk = 32; msk; msk >>= 1) zsq += __shfl_down(zsq, msk, 64);
        if (lane == 0) atomicAdd(zsq_acc, zsq);
    }

    // ----- per-wave argmin over its 32 codes; D: px row = quad*4+r, code col = m
    float c2v[2];
    #pragma unroll
    for (int ct = 0; ct < 2; ct++) c2v[ct] = ce2[w * 32 + ct * 16 + m];
    #pragma unroll
    for (int at = 0; at < 4; at++) {
        #pragma unroll
        for (int r = 0; r < 4; r++) {
            float v1 = 3.4e38f, v2 = 3.4e38f; int i1 = 0;
            #pragma unroll
            for (int ct = 0; ct < 2; ct++) {
                int code = w * 32 + ct * 16 + m;
                float sv = c2v[ct] - acc[at][ct][r];   // 0.5||e||^2 - z.e
                if (sv < v1 || (sv == v1 && code < i1)) { v2 = v1; v1 = sv; i1 = code; }
                else v2 = fminf(v2, sv);
            }
            #pragma unroll
            for (int msk = 1; msk < 16; msk <<= 1) {
                float ov1 = __shfl_xor(v1, msk, 64);
                int   oi1 = __shfl_xor(i1, msk, 64);
                float ov2 = __shfl_xor(v2, msk, 64);
                float nv2 = fminf(fminf(v2, ov2), fmaxf(v1, ov1));
                if (ov1 < v1 || (ov1 == v1 && oi1 < i1)) { v1 = ov1; i1 = oi1; }
                v2 = nv2;
            }
            if (m == 0) {
                int pxl = at * 16 + quad * 4 + r;
                int e = (w * 64 + pxl) * 3;
                red[e] = v1; ((int*)red)[e + 1] = i1; red[e + 2] = v2;
            }
        }
    }
    __syncthreads();
    if (t < 64) {   // wave 0: combine 8 wave-entries per pixel
        float v1 = red[t * 3], v2 = red[t * 3 + 2];
        int i1 = ((int*)red)[t * 3 + 1];
        #pragma unroll
        for (int ww = 1; ww < 8; ww++) {
            int e = (ww * 64 + t) * 3;
            float ov1 = red[e], ov2 = red[e + 2];
            int oi1 = ((int*)red)[e + 1];
            float nv2 = fminf(fminf(v2, ov2), fmaxf(v1, ov1));
            if (ov1 < v1 || (ov1 == v1 && oi1 < i1)) { v1 = ov1; i1 = oi1; }
            v2 = nv2;
        }
        int px = px0 + t;
        idx_i[px] = i1;
        idx_f[px] = (float)i1;
        atomicAdd(&hist[i1], 1);
        if (v2 - v1 < DELTA)
            atomicOr(&fbits[px >> 5], 1u << (px & 31));
        float ls = v1;
        #pragma unroll
        for (int msk = 32; msk; msk >>= 1) ls += __shfl_down(ls, msk, 64);
        if (t == 0) atomicAdd(loss_s, ls);
    }
}

// ---------------- exact fp32 re-argmin for tie-flagged pixels --------------
__global__ __launch_bounds__(256) void k_cleanup(const float* __restrict__ z,
        const float* __restrict__ emb, const float* __restrict__ ce2,
        const unsigned int* __restrict__ fbits,
        int* __restrict__ idx_i, float* __restrict__ idx_f, int* __restrict__ hist) {
    __shared__ float zs[1024];
    __shared__ float rv[4];
    __shared__ int ri[4];
    int t = threadIdx.x;
    const float* er = emb + (size_t)t * EDIM;
    for (int px = blockIdx.x; px < NPIX; px += gridDim.x) {
        if (!(fbits[px >> 5] & (1u << (px & 31)))) continue;   // uniform per block
        int b = px >> 10, p = px & 1023;
        const float* zb = z + (((size_t)b) << 20) + p;
        #pragma unroll
        for (int r = 0; r < 4; r++) {
            int c = t + 256 * r;
            zs[c] = zb[((size_t)c) << 10];
        }
        __syncthreads();
        float d0 = 0.f, d1 = 0.f, d2 = 0.f, d3 = 0.f;
        #pragma unroll 4
        for (int c = 0; c < EDIM; c += 16) {
            float4 e0 = *(const float4*)(er + c);
            float4 e1 = *(const float4*)(er + c + 4);
            float4 e2 = *(const float4*)(er + c + 8);
            float4 e3 = *(const float4*)(er + c + 12);
            d0 += e0.x * zs[c]      + e0.y * zs[c + 1]  + e0.z * zs[c + 2]  + e0.w * zs[c + 3];
            d1 += e1.x * zs[c + 4]  + e1.y * zs[c + 5]  + e1.z * zs[c + 6]  + e1.w * zs[c + 7];
            d2 += e2.x * zs[c + 8]  + e2.y * zs[c + 9]  + e2.z * zs[c + 10] + e2.w * zs[c + 11];
            d3 += e3.x * zs[c + 12] + e3.y * zs[c + 13] + e3.z * zs[c + 14] + e3.w * zs[c + 15];
        }
        float sv = ce2[t] - ((d0 + d1) + (d2 + d3));
        int bi = t;
        #pragma unroll
        for (int msk = 1; msk < 64; msk <<= 1) {
            float ov = __shfl_xor(sv, msk, 64);
            int oi = __shfl_xor(bi, msk, 64);
            if (ov < sv || (ov == sv && oi < bi)) { sv = ov; bi = oi; }
        }
        if ((t & 63) == 0) { rv[t >> 6] = sv; ri[t >> 6] = bi; }
        __syncthreads();
        if (t == 0) {
            float v = rv[0]; int ix = ri[0];
            for (int ww = 1; ww < 4; ww++)
                if (rv[ww] < v || (rv[ww] == v && ri[ww] < ix)) { v = rv[ww]; ix = ri[ww]; }
            int old = idx_i[px];
            if (ix != old) {
                idx_i[px] = ix; idx_f[px] = (float)ix;
                atomicAdd(&hist[ix], 1); atomicSub(&hist[old], 1);
            }
        }
        __syncthreads();
    }
}

// ------- scatter + fused finalize: out[b][o][p] = T[o][idx[b][p]] + bias[o]
__global__ __launch_bounds__(256) void k_scatter_f(const float* __restrict__ T,
                                                   const float* __restrict__ bias,
                                                   const int* __restrict__ idx,
                                                   const int* __restrict__ hist,
                                                   const float* __restrict__ loss_s,
                                                   const float* __restrict__ zsq,
                                                   float* __restrict__ out) {
    __shared__ float Ts[16 * 256];
    __shared__ float bs[16];
    __shared__ float red2[4];
    int t = threadIdx.x;
    int o0 = blockIdx.x * 16;
    int b = blockIdx.y;
    if (blockIdx.x == 0 && blockIdx.y == 0) {   // fused k_final
        float em = (float)hist[t] * (1.0f / 16384.0f);
        float v = em * logf(em + 1e-10f);
        #pragma unroll
        for (int m = 32; m; m >>= 1) v += __shfl_down(v, m, 64);
        if ((t & 63) == 0) red2[t >> 6] = v;
        __syncthreads();
        if (t == 0) {
            float s = red2[0] + red2[1] + red2[2] + red2[3];
            out[OUT_ELEMS] = (zsq[0] + 2.f * loss_s[0]) * 1.25f / 16777216.f;
            out[OUT_ELEMS + 1] = expf(-s);
        }
    }
    #pragma unroll
    for (int r = 0; r < 16; r++)
        Ts[r * 256 + t] = T[(size_t)(o0 + r) * NE + t];
    if (t < 16) bs[t] = bias[o0 + t];
    __syncthreads();
    int4 i4 = *(const int4*)(idx + b * HW + t * 4);
    #pragma unroll
    for (int r = 0; r < 16; r++) {
        const float* Tr = Ts + r * 256;
        float bb = bs[r];
        float4 v;
        v.x = Tr[i4.x] + bb;
        v.y = Tr[i4.y] + bb;
        v.z = Tr[i4.z] + bb;
        v.w = Tr[i4.w] + bb;
        *(float4*)(out + ((size_t)(b * EDIM + o0 + r) * HW) + t * 4) = v;
    }
}

// ================= fallback (round-1 fp32 path) kernels ====================
__global__ __launch_bounds__(64) void k_norms(const float* __restrict__ emb,
                                              float* __restrict__ ce2) {
    int j = blockIdx.x;
    int lane = threadIdx.x;
    const float* row = emb + (size_t)j * EDIM;
    float s = 0.f;
    #pragma unroll
    for (int i = 0; i < EDIM / 64; i++) {
        float v = row[lane + 64 * i];
        s += v * v;
    }
    #pragma unroll
    for (int m = 32; m; m >>= 1) s += __shfl_down(s, m, 64);
    if (lane == 0) ce2[j] = 0.5f * s;
}

__global__ __launch_bounds__(256) void k_argmin(const float* __restrict__ z,
                                                const float* __restrict__ emb,
                                                const float* __restrict__ ce2,
                                                int* __restrict__ idx_i,
                                                float* __restrict__ idx_f,
                                                int* __restrict__ hist,
                                                float* __restrict__ loss_acc) {
    __shared__ float zt[32 * 64];
    __shared__ float et[256 * 34];
    __shared__ float znorm_s[64];
    int t = threadIdx.x;
    int n0 = blockIdx.x * 64;
    int b = n0 >> 10;
    int p0 = n0 & 1023;
    const float* zb = z + (size_t)b * EDIM * HW;
    int tc = t & 31, tp = t >> 5;
    float acc[8][8] = {};
    float znorm = 0.f;
    for (int kk = 0; kk < EDIM; kk += 32) {
        #pragma unroll
        for (int i = 0; i < 16; i++) {
            int q = t + 256 * i;
            int code = q >> 4, k2 = q & 15;
            float2 v = *(const float2*)(emb + (size_t)code * EDIM + kk + k2 * 2);
            *(float2*)(et + code * 34 + k2 * 2) = v;
        }
        #pragma unroll
        for (int i = 0; i < 4; i++) {
            int q = t + 256 * i;
            int k = q >> 5, p2 = q & 31;
            float2 v = *(const float2*)(zb + (size_t)(kk + k) * HW + p0 + p2 * 2);
            *(float2*)(zt + k * 64 + p2 * 2) = v;
        }
        __syncthreads();
        if (t < 64) {
            #pragma unroll
            for (int k = 0; k < 32; k++) { float zz = zt[k * 64 + t]; znorm += zz * zz; }
        }
        #pragma unroll 4
        for (int k2 = 0; k2 < 16; k2++) {
            float2 ev[8], za[4], zb2[4];
            #pragma unroll
            for (int u = 0; u < 8; u++)
                ev[u] = *(float2*)(et + (tc + 32 * u) * 34 + k2 * 2);
            #pragma unroll
            for (int j = 0; j < 4; j++)
                za[j] = *(float2*)(zt + (2 * k2) * 64 + tp * 8 + 2 * j);
            #pragma unroll
            for (int j = 0; j < 4; j++)
                zb2[j] = *(float2*)(zt + (2 * k2 + 1) * 64 + tp * 8 + 2 * j);
            #pragma unroll
            for (int p = 0; p < 8; p++) {
                float z0 = (p & 1) ? za[p >> 1].y : za[p >> 1].x;
                float z1 = (p & 1) ? zb2[p >> 1].y : zb2[p >> 1].x;
                #pragma unroll
                for (int u = 0; u < 8; u++)
                    acc[p][u] += z0 * ev[u].x + z1 * ev[u].y;
            }
        }
        __syncthreads();
    }
    if (t < 64) znorm_s[t] = znorm;
    float minv[8];
    int mini[8];
    #pragma unroll
    for (int p = 0; p < 8; p++) { minv[p] = 3.4e38f; mini[p] = 0; }
    #pragma unroll
    for (int u = 0; u < 8; u++) {
        int code = tc + 32 * u;
        float cc2 = ce2[code];
        #pragma unroll
        for (int p = 0; p < 8; p++) {
            float s = cc2 - acc[p][u];
            if (s < minv[p] || (s == minv[p] && code < mini[p])) { minv[p] = s; mini[p] = code; }
        }
    }
    #pragma unroll
    for (int m = 1; m < 32; m <<= 1) {
        #pragma unroll
        for (int p = 0; p < 8; p++) {
            float ov = __shfl_xor(minv[p], m, 64);
            int oi = __shfl_xor(mini[p], m, 64);
            if (ov < minv[p] || (ov == minv[p] && oi < mini[p])) { minv[p] = ov; mini[p] = oi; }
        }
    }
    __syncthreads();
    if (tc == 0) {
        float dsum = 0.f;
        #pragma unroll
        for (int p = 0; p < 8; p++) {
            int lp = tp * 8 + p;
            int n = n0 + lp;
            idx_i[n] = mini[p];
            idx_f[n] = (float)mini[p];
            dsum += znorm_s[lp] + 2.f * minv[p];
            atomicAdd(&hist[mini[p]], 1);
        }
        atomicAdd(loss_acc, dsum);
    }
}

__global__ __launch_bounds__(256) void k_scatter(const float* __restrict__ T,
                                                 const float* __restrict__ bias,
                                                 const int* __restrict__ idx,
                                                 float* __restrict__ out) {
    __shared__ float Ts[16 * 256];
    __shared__ float bs[16];
    int t = threadIdx.x;
    int o0 = blockIdx.x * 16;
    int b = blockIdx.y;
    #pragma unroll
    for (int r = 0; r < 16; r++)
        Ts[r * 256 + t] = T[(size_t)(o0 + r) * NE + t];
    if (t < 16) bs[t] = bias[o0 + t];
    __syncthreads();
    int4 i4 = *(const int4*)(idx + b * HW + t * 4);
    #pragma unroll
    for (int r = 0; r < 16; r++) {
        const float* Tr = Ts + r * 256;
        float bb = bs[r];
        float4 v;
        v.x = Tr[i4.x] + bb;
        v.y = Tr[i4.y] + bb;
        v.z = Tr[i4.z] + bb;
        v.w = Tr[i4.w] + bb;
        *(float4*)(out + ((size_t)(b * EDIM + o0 + r) * HW) + t * 4) = v;
    }
}

__global__ __launch_bounds__(256) void k_final_old(const int* __restrict__ hist,
                                                   const float* __restrict__ loss_acc,
                                                   float* __restrict__ out) {
    __shared__ float red[4];
    int t = threadIdx.x;
    float em = (float)hist[t] * (1.0f / 16384.0f);
    float v = em * logf(em + 1e-10f);
    #pragma unroll
    for (int m = 32; m; m >>= 1) v += __shfl_down(v, m, 64);
    if ((t & 63) == 0) red[t >> 6] = v;
    __syncthreads();
    if (t == 0) {
        float s = red[0] + red[1] + red[2] + red[3];
        out[OUT_ELEMS] = loss_acc[0] * 1.25f / 16777216.f;
        out[OUT_ELEMS + 1] = expf(-s);
    }
}

extern "C" void kernel_launch(void* const* d_in, const int* in_sizes, int n_in,
                              void* d_out, int out_size, void* d_ws, size_t ws_size,
                              hipStream_t stream) {
    (void)in_sizes; (void)n_in; (void)out_size;
    const float* z      = (const float*)d_in[0];
    const float* emb    = (const float*)d_in[1];
    const float* conv_w = (const float*)d_in[2];
    const float* conv_b = (const float*)d_in[3];
    float* out = (float*)d_out;

    if (ws_size >= WS_NEED) {
        // ---- fast path: code-split 8-wave bf16x3 MFMA distance GEMM ----
        int*   hist     = (int*)((char*)d_ws + WS_HIST);
        float* loss_s   = (float*)((char*)d_ws + WS_LOSS);
        float* zsq      = (float*)((char*)d_ws + WS_ZSQ);
        unsigned int* fbits = (unsigned int*)((char*)d_ws + WS_FBITS);
        float* T        = (float*)((char*)d_ws + WS_T);
        float* ce2      = (float*)((char*)d_ws + WS_CE2);
        int*   idx_i    = (int*)((char*)d_ws + WS_IDX);
        unsigned short* ehs = (unsigned short*)((char*)d_ws + WS_EH);
        unsigned short* els = (unsigned short*)((char*)d_ws + WS_EL);
        float* idx_f = out + OUT_ELEMS + 2;

        k_prep<<<NE, 64, 0, stream>>>(emb, ehs, els, ce2, T, (unsigned char*)d_ws);
        k_wT<<<dim3(4, 16, 4), 256, 0, stream>>>(conv_w, emb, T);
        k_dist<<<256, 512, 0, stream>>>(z, ehs, els, ce2, idx_i, idx_f,
                                        hist, loss_s, zsq, fbits);
        k_cleanup<<<256, 256, 0, stream>>>(z, emb, ce2, fbits, idx_i, idx_f, hist);
        k_scatter_f<<<dim3(64, 16), 256, 0, stream>>>(T, conv_b, idx_i, hist,
                                                      loss_s, zsq, out);
    } else {
        // ---- fallback: round-1 fp32 path ----
        float* ce2      = (float*)((char*)d_ws + WO_CE2);
        int*   hist     = (int*)((char*)d_ws + WO_HIST);
        float* loss_acc = (float*)((char*)d_ws + WO_LOSS);
        int*   idx_i    = (int*)((char*)d_ws + WO_IDX);
        float* T        = (float*)((char*)d_ws + WO_T);
        float* idx_f = out + OUT_ELEMS + 2;

        hipMemsetAsync(d_ws, 0, WO_TOTAL, stream);
        k_norms<<<NE, 64, 0, stream>>>(emb, ce2);
        k_wT<<<dim3(4, 16, 4), 256, 0, stream>>>(conv_w, emb, T);
        k_argmin<<<256, 256, 0, stream>>>(z, emb, ce2, idx_i, idx_f, hist, loss_acc);
        k_scatter<<<dim3(64, 16), 256, 0, stream>>>(T, conv_b, idx_i, out);
        k_final_old<<<1, 256, 0, stream>>>(hist, loss_acc, out);
    }
}